// Round 7
// baseline (137.619 us; speedup 1.0000x reference)
//
#include <hip/hip_runtime.h>

#define IN_DIM 256
#define HID 128

using bf16x8 = __attribute__((ext_vector_type(8))) short;
using f32x4 = __attribute__((ext_vector_type(4))) float;

__device__ __forceinline__ unsigned short f2bf(float f) {
    unsigned u = __float_as_uint(f);
    u += 0x7fffu + ((u >> 16) & 1u);  // RNE (inputs finite)
    return (unsigned short)(u >> 16);
}

// ---------- merged weight transpose+convert for the 3 live weights ----------
// layout: W[K][128] fp32 -> Wt[K/8][128][8] bf16
__device__ __forceinline__ void wt_cvt_one(const float* __restrict__ W,
                                           short* __restrict__ Wt, int idx) {
    const int kkblk = idx >> 10;
    const int n = (idx >> 3) & 127;
    const int t = idx & 7;
    const int k = (kkblk << 3) | t;
    Wt[idx] = (short)f2bf(W[(size_t)k * HID + n]);
}

__global__ __launch_bounds__(256) void wtcvt3_k(const float* __restrict__ linW0,
                                                const float* __restrict__ Ws0,
                                                const float* __restrict__ Ws5,
                                                short* __restrict__ wtl,
                                                short* __restrict__ wtc0,
                                                short* __restrict__ wtc5) {
    const int idx = blockIdx.x * blockDim.x + threadIdx.x;
    if (idx < 32768) {
        wt_cvt_one(linW0, wtl, idx);
    } else if (idx < 49152) {
        wt_cvt_one(Ws0, wtc0, idx - 32768);
    } else if (idx < 65536) {
        wt_cvt_one(Ws5, wtc5, idx - 49152);
    }
}

// ---------- single-block: wd{1,2} = Wd[l,0]@ad[l,0]; v2 = linW2@wd1; c2 = linb2·wd1 ----
__global__ __launch_bounds__(256) void wdv2_k(const float* __restrict__ Wd,
                                              const float* __restrict__ ad,
                                              const float* __restrict__ lin_W,
                                              const float* __restrict__ lin_b,
                                              float* __restrict__ wd_out,  // [2*128]
                                              float* __restrict__ v2,      // [256]
                                              float* __restrict__ c2) {
    __shared__ float wd1s[HID];
    const int t = threadIdx.x;  // 0..255
    const int l = t >> 7, j = t & 127;
    const float* w = Wd + ((size_t)(l * 5) * HID + j) * HID;
    const float* a = ad + (size_t)(l * 5) * HID;
    float s = 0.f;
    for (int k = 0; k < HID; ++k) s += w[k] * a[k];
    wd_out[t] = s;
    if (l == 0) wd1s[j] = s;
    __syncthreads();
    const float* wr = lin_W + 2 * (size_t)IN_DIM * HID + (size_t)t * HID;
    float p = 0.f;
    for (int k = 0; k < HID; ++k) p += wr[k] * wd1s[k];
    v2[t] = p;
    if (t == 0) {
        const float* br = lin_b + 2 * HID;
        float q = 0.f;
        for (int k = 0; k < HID; ++k) q += br[k] * wd1s[k];
        c2[0] = q;
    }
}

// ---------- MFMA GEMM (single weight): C[N,128] = A[N,K] @ Wt (+bias) ----------
template <int K>
__global__ __launch_bounds__(256) void gemm_mfma(const float* __restrict__ A,
                                                 const short* __restrict__ Wt,
                                                 const float* __restrict__ bias,
                                                 float* __restrict__ C, int N) {
    const int tid = threadIdx.x;
    const int w = tid >> 6;
    const int lane = tid & 63;
    const int m16 = lane & 15;
    const int kg = lane >> 4;

    const int arow = blockIdx.x * 64 + w * 16 + m16;
    const bool ok = arow < N;

    f32x4 acc[8];
#pragma unroll
    for (int j = 0; j < 8; ++j) acc[j] = (f32x4){0.f, 0.f, 0.f, 0.f};

    for (int k0 = 0; k0 < K; k0 += 32) {
        bf16x8 af = {0, 0, 0, 0, 0, 0, 0, 0};
        if (ok) {
            const float* ap = A + (size_t)arow * K + k0 + kg * 8;
            const float4 f0 = *reinterpret_cast<const float4*>(ap);
            const float4 f1 = *reinterpret_cast<const float4*>(ap + 4);
            af[0] = (short)f2bf(f0.x); af[1] = (short)f2bf(f0.y);
            af[2] = (short)f2bf(f0.z); af[3] = (short)f2bf(f0.w);
            af[4] = (short)f2bf(f1.x); af[5] = (short)f2bf(f1.y);
            af[6] = (short)f2bf(f1.z); af[7] = (short)f2bf(f1.w);
        }
        const short* bbase = Wt + (((k0 >> 3) + kg) << 10);
#pragma unroll
        for (int j = 0; j < 8; ++j) {
            const bf16x8 bf = *reinterpret_cast<const bf16x8*>(bbase + ((j * 16 + m16) << 3));
            acc[j] = __builtin_amdgcn_mfma_f32_16x16x32_bf16(af, bf, acc[j], 0, 0, 0);
        }
    }

    const int rbase = blockIdx.x * 64 + w * 16 + kg * 4;
    float bj[8];
#pragma unroll
    for (int j = 0; j < 8; ++j) bj[j] = bias ? bias[j * 16 + m16] : 0.f;
#pragma unroll
    for (int j = 0; j < 8; ++j)
#pragma unroll
        for (int r = 0; r < 4; ++r) {
            const int row = rbase + r;
            if (row < N) C[(size_t)row * HID + j * 16 + m16] = acc[j][r] + bj[j];
        }
}

// ---------- dual MFMA GEMM: hs[N][256] = A[N,128] @ {Wt0|Wt1}, fused as1/as2 ----------
__global__ __launch_bounds__(256) void gemm_dual_k(const float* __restrict__ A,
                                                   const short* __restrict__ Wt0,
                                                   const short* __restrict__ Wt1,
                                                   float* __restrict__ C,
                                                   float* __restrict__ as1,
                                                   float* __restrict__ as2,
                                                   const float* __restrict__ a1v,
                                                   const float* __restrict__ a2v, int N) {
    const int tid = threadIdx.x;
    const int w = tid >> 6;
    const int lane = tid & 63;
    const int m16 = lane & 15;
    const int kg = lane >> 4;

    const int arow = blockIdx.x * 64 + w * 16 + m16;
    const bool ok = arow < N;

    f32x4 acc[16];
#pragma unroll
    for (int j = 0; j < 16; ++j) acc[j] = (f32x4){0.f, 0.f, 0.f, 0.f};

    for (int k0 = 0; k0 < HID; k0 += 32) {
        bf16x8 af = {0, 0, 0, 0, 0, 0, 0, 0};
        if (ok) {
            const float* ap = A + (size_t)arow * HID + k0 + kg * 8;
            const float4 f0 = *reinterpret_cast<const float4*>(ap);
            const float4 f1 = *reinterpret_cast<const float4*>(ap + 4);
            af[0] = (short)f2bf(f0.x); af[1] = (short)f2bf(f0.y);
            af[2] = (short)f2bf(f0.z); af[3] = (short)f2bf(f0.w);
            af[4] = (short)f2bf(f1.x); af[5] = (short)f2bf(f1.y);
            af[6] = (short)f2bf(f1.z); af[7] = (short)f2bf(f1.w);
        }
        const int boff = ((k0 >> 3) + kg) << 10;
        const short* b0 = Wt0 + boff;
        const short* b1 = Wt1 + boff;
#pragma unroll
        for (int j = 0; j < 8; ++j) {
            const bf16x8 bf0 = *reinterpret_cast<const bf16x8*>(b0 + ((j * 16 + m16) << 3));
            acc[j] = __builtin_amdgcn_mfma_f32_16x16x32_bf16(af, bf0, acc[j], 0, 0, 0);
            const bf16x8 bf1 = *reinterpret_cast<const bf16x8*>(b1 + ((j * 16 + m16) << 3));
            acc[j + 8] = __builtin_amdgcn_mfma_f32_16x16x32_bf16(af, bf1, acc[j + 8], 0, 0, 0);
        }
    }

    const int rbase = blockIdx.x * 64 + w * 16 + kg * 4;
#pragma unroll
    for (int j = 0; j < 16; ++j)
#pragma unroll
        for (int r = 0; r < 4; ++r) {
            const int row = rbase + r;
            if (row < N) C[(size_t)row * 256 + j * 16 + m16] = acc[j][r];
        }

    float p1[4] = {0.f, 0.f, 0.f, 0.f};
    float p2[4] = {0.f, 0.f, 0.f, 0.f};
#pragma unroll
    for (int j = 0; j < 8; ++j) {
        const float a1 = a1v[j * 16 + m16];
        const float a2 = a2v[j * 16 + m16];
#pragma unroll
        for (int r = 0; r < 4; ++r) {
            p1[r] += acc[j][r] * a1;
            p2[r] += acc[j + 8][r] * a2;
        }
    }
#pragma unroll
    for (int off = 8; off > 0; off >>= 1)
#pragma unroll
        for (int r = 0; r < 4; ++r) {
            p1[r] += __shfl_xor(p1[r], off, 64);
            p2[r] += __shfl_xor(p2[r], off, 64);
        }
    if (m16 == 0)
#pragma unroll
        for (int r = 0; r < 4; ++r) {
            const int row = rbase + r;
            if (row < N) {
                as1[row] = p1[r];
                as2[row] = p2[r];
            }
        }
}

// ================= CSR build for the single live relation ==========
__global__ __launch_bounds__(256) void hist_k(const int* __restrict__ dst,
                                              int* __restrict__ deg, int E) {
    const int e = blockIdx.x * blockDim.x + threadIdx.x;
    if (e < E) atomicAdd(deg + dst[e], 1);
}

__global__ __launch_bounds__(256) void scan_partial_k(const int* __restrict__ deg,
                                                      int* __restrict__ partial, int total) {
    const int tid = threadIdx.x;
    const int base = blockIdx.x * 1024 + tid * 4;
    int s = 0;
#pragma unroll
    for (int i = 0; i < 4; ++i) {
        const int idx = base + i;
        if (idx < total) s += deg[idx];
    }
    __shared__ int red[4];
    int w = s;
#pragma unroll
    for (int off = 32; off > 0; off >>= 1) w += __shfl_xor(w, off, 64);
    if ((tid & 63) == 0) red[tid >> 6] = w;
    __syncthreads();
    if (tid == 0) partial[blockIdx.x] = red[0] + red[1] + red[2] + red[3];
}

__global__ __launch_bounds__(256) void scan_partials_k(int* __restrict__ partial, int nb) {
    __shared__ int sc[256];
    const int tid = threadIdx.x;
    const int v = (tid < nb) ? partial[tid] : 0;
    sc[tid] = v;
    __syncthreads();
    for (int off = 1; off < 256; off <<= 1) {
        const int u = (tid >= off) ? sc[tid - off] : 0;
        __syncthreads();
        sc[tid] += u;
        __syncthreads();
    }
    if (tid < nb) partial[tid] = sc[tid] - v;  // exclusive
}

__global__ __launch_bounds__(256) void scan_write_k(const int* __restrict__ deg,
                                                    const int* __restrict__ partial,
                                                    int* __restrict__ row_ptr,
                                                    int* __restrict__ cursor, int total,
                                                    int grand_total) {
    const int tid = threadIdx.x;
    const int base = blockIdx.x * 1024 + tid * 4;
    int v[4];
    int s = 0;
#pragma unroll
    for (int i = 0; i < 4; ++i) {
        const int idx = base + i;
        v[i] = (idx < total) ? deg[idx] : 0;
        s += v[i];
    }
    __shared__ int sc[256];
    sc[tid] = s;
    __syncthreads();
    for (int off = 1; off < 256; off <<= 1) {
        const int u = (tid >= off) ? sc[tid - off] : 0;
        __syncthreads();
        sc[tid] += u;
        __syncthreads();
    }
    int run = partial[blockIdx.x] + sc[tid] - s;
#pragma unroll
    for (int i = 0; i < 4; ++i) {
        const int idx = base + i;
        if (idx < total) {
            row_ptr[idx] = run;
            cursor[idx] = run;
            run += v[i];
        }
    }
    if (blockIdx.x == 0 && tid == 0) row_ptr[total] = grand_total;
}

__global__ __launch_bounds__(256) void scatter_k(const int* __restrict__ src,
                                                 const int* __restrict__ dst,
                                                 int* __restrict__ cursor,
                                                 int* __restrict__ col, int E) {
    const int e = blockIdx.x * blockDim.x + threadIdx.x;
    if (e >= E) return;
    const int pos = atomicAdd(cursor + dst[e], 1);
    col[pos] = src[e];
}

// ========== fully fused 2-layer GAT, 16 lanes per dst row (4 rows/wave) ==========
// per row: ad1 = x_span·v2+c2 -> layer1 softmax+gather -> ad2 = relu(+b1)·wd2
//          -> layer2 softmax+gather -> out = relu(+b2)·outW + outb
__global__ __launch_bounds__(256) void gat_fused_k(
    const int* __restrict__ row_ptr, const int* __restrict__ col,
    const float* __restrict__ x_span, const float* __restrict__ v2,
    const float* __restrict__ c2, const float* __restrict__ as1,
    const float* __restrict__ as2, const float* __restrict__ hs,
    const float* __restrict__ b1, const float* __restrict__ wd2v,
    const float* __restrict__ b2, const float* __restrict__ outW,
    const float* __restrict__ outb, float* __restrict__ out, int Ndst) {
    const int gidx = blockIdx.x * blockDim.x + threadIdx.x;
    const int row = gidx >> 4;
    const int sl = threadIdx.x & 15;
    if (row >= Ndst) return;
    const int beg = row_ptr[row];
    const int end = row_ptr[row + 1];

    // ---- ad1 ----
    float p = 0.f;
    const float* xr = x_span + (size_t)row * IN_DIM + sl * 16;
    const float* vr = v2 + sl * 16;
#pragma unroll
    for (int i = 0; i < 4; ++i) {
        const float4 xv = *reinterpret_cast<const float4*>(xr + i * 4);
        const float4 vv = *reinterpret_cast<const float4*>(vr + i * 4);
        p += xv.x * vv.x + xv.y * vv.y + xv.z * vv.z + xv.w * vv.w;
    }
#pragma unroll
    for (int off = 8; off > 0; off >>= 1) p += __shfl_xor(p, off, 64);
    float ad = p + c2[0];

#pragma unroll
    for (int layer = 0; layer < 2; ++layer) {
        const float* as_s = layer ? as2 : as1;
        const int hoff = layer ? HID : 0;
        const float* bias = layer ? b2 : b1;
        const float* dvec = layer ? outW : wd2v;

        // online max + denom (16 edges/batch; usually 1 batch)
        float m = -INFINITY, dsum = 0.f;
        for (int base = beg; base < end; base += 16) {
            const int e = base + sl;
            float ev = -INFINITY;
            if (e < end) {
                const float t0 = as_s[col[e]] + ad;
                ev = t0 > 0.f ? t0 : 0.2f * t0;
            }
            float gm = ev;
#pragma unroll
            for (int off = 8; off > 0; off >>= 1) gm = fmaxf(gm, __shfl_xor(gm, off, 64));
            float ex = (e < end) ? expf(ev - gm) : 0.f;
#pragma unroll
            for (int off = 8; off > 0; off >>= 1) ex += __shfl_xor(ex, off, 64);
            dsum = dsum * expf(m - gm) + ex;
            m = gm;
        }
        const float inv = 1.f / (dsum + 1e-16f);

        // serial gather: 16 lanes read 512B row (32B/lane)
        f32x4 acc0 = {0.f, 0.f, 0.f, 0.f}, acc1 = {0.f, 0.f, 0.f, 0.f};
        for (int e = beg; e < end; ++e) {
            const int s = col[e];
            float t0 = as_s[s] + ad;
            t0 = t0 > 0.f ? t0 : 0.2f * t0;
            const float alpha = expf(t0 - m) * inv;
            const float* h = hs + (size_t)s * 256 + hoff + sl * 8;
            const f32x4 h0 = *reinterpret_cast<const f32x4*>(h);
            const f32x4 h1 = *reinterpret_cast<const f32x4*>(h + 4);
#pragma unroll
            for (int i = 0; i < 4; ++i) {
                acc0[i] += alpha * h0[i];
                acc1[i] += alpha * h1[i];
            }
        }

        // epilogue: relu(acc+bias)·dvec, 16-lane reduce
        const f32x4 bb0 = *reinterpret_cast<const f32x4*>(bias + sl * 8);
        const f32x4 bb1 = *reinterpret_cast<const f32x4*>(bias + sl * 8 + 4);
        const f32x4 d0 = *reinterpret_cast<const f32x4*>(dvec + sl * 8);
        const f32x4 d1 = *reinterpret_cast<const f32x4*>(dvec + sl * 8 + 4);
        float q = 0.f;
#pragma unroll
        for (int i = 0; i < 4; ++i) {
            q += fmaxf(acc0[i] + bb0[i], 0.f) * d0[i];
            q += fmaxf(acc1[i] + bb1[i], 0.f) * d1[i];
        }
#pragma unroll
        for (int off = 8; off > 0; off >>= 1) q += __shfl_xor(q, off, 64);
        if (layer == 0) {
            ad = q;  // becomes ad2 for layer 2 (uniform across the 16-lane group)
        } else if (sl == 0) {
            out[row] = q + outb[0];
        }
    }
}

extern "C" void kernel_launch(void* const* d_in, const int* in_sizes, int n_in,
                              void* d_out, int out_size, void* d_ws, size_t ws_size,
                              hipStream_t stream) {
    // Live dataflow: out = relu(gat2)·outW + outb over QENT->SPAN only (see R4/R5).
    const float* x_qent = (const float*)d_in[0];
    const float* x_span = (const float*)d_in[2];
    const int* e_qs = (const int*)d_in[4];  // [2][E]
    const float* lin_W = (const float*)d_in[9];
    const float* lin_b = (const float*)d_in[10];
    const float* conv_Ws = (const float*)d_in[11];
    const float* conv_Wd = (const float*)d_in[12];
    const float* conv_as = (const float*)d_in[13];
    const float* conv_ad = (const float*)d_in[14];
    const float* conv_b = (const float*)d_in[15];
    const float* out_W = (const float*)d_in[16];
    const float* out_b = (const float*)d_in[17];

    const int NQ = in_sizes[0] / IN_DIM;
    const int NS = in_sizes[2] / IN_DIM;
    const int E = in_sizes[4] / 2;
    const int* srcp = e_qs;
    const int* dstp = e_qs + E;
    (void)n_in; (void)out_size;

    // ---- workspace carve ----
    float* ws = (float*)d_ws;
    size_t off = 0;
    auto alloc = [&](size_t n) { float* p = ws + off; off += n; return p; };
    float* xq = alloc((size_t)NQ * HID);
    float* hs = alloc((size_t)NQ * 256);  // [NQ][256]: cols 0:128 L1, 128:256 L2
    float* as1 = alloc(NQ);
    float* as2 = alloc(NQ);
    float* wd2 = alloc(2 * HID);
    float* v2 = alloc(IN_DIM);
    float* c2 = alloc(1);
    int* deg = (int*)alloc(NS);
    int* cursor = (int*)alloc(NS);
    int* row_ptr = (int*)alloc((size_t)NS + 1);
    int* partial = (int*)alloc(256);
    int* col = (int*)alloc(E);
    short* wt_lin0 = (short*)alloc(IN_DIM * HID / 2);
    short* wt_conv0 = (short*)alloc(HID * HID / 2);
    short* wt_conv5 = (short*)alloc(HID * HID / 2);
    (void)ws_size;

    // 0a. merged weight convert + merged wd/v2/c2 prep
    wtcvt3_k<<<dim3(65536 / 256), dim3(256), 0, stream>>>(
        lin_W, conv_Ws, conv_Ws + 5 * (size_t)HID * HID, wt_lin0, wt_conv0, wt_conv5);
    wdv2_k<<<dim3(1), dim3(256), 0, stream>>>(conv_Wd, conv_ad, lin_W, lin_b, wd2, v2, c2);

    // 0b. dst-CSR for r0
    const int nb = (NS + 1023) / 1024;
    hipMemsetAsync(deg, 0, (size_t)NS * 4, stream);
    hist_k<<<dim3((E + 255) / 256), dim3(256), 0, stream>>>(dstp, deg, E);
    scan_partial_k<<<dim3(nb), dim3(256), 0, stream>>>(deg, partial, NS);
    scan_partials_k<<<dim3(1), dim3(256), 0, stream>>>(partial, nb);
    scan_write_k<<<dim3(nb), dim3(256), 0, stream>>>(deg, partial, row_ptr, cursor, NS, E);
    scatter_k<<<dim3((E + 255) / 256), dim3(256), 0, stream>>>(srcp, dstp, cursor, col, E);

    // 1. QENT projection, then both layers' hs + fused as1/as2
    gemm_mfma<IN_DIM><<<dim3((NQ + 63) / 64), dim3(256), 0, stream>>>(
        x_qent, wt_lin0, lin_b, xq, NQ);
    gemm_dual_k<<<dim3((NQ + 63) / 64), dim3(256), 0, stream>>>(
        xq, wt_conv0, wt_conv5, hs, as1, as2, conv_as, conv_as + 5 * (size_t)HID, NQ);

    // 2. one fused kernel: ad1 matvec + both GAT layers + final projection
    gat_fused_k<<<dim3(((size_t)NS * 16 + 255) / 256), dim3(256), 0, stream>>>(
        row_ptr, col, x_span, v2, c2, as1, as2, hs, conv_b, wd2 + HID,
        conv_b + 5 * (size_t)HID, out_W, out_b, (float*)d_out, NS);
}

// Round 8
// 131.592 us; speedup vs baseline: 1.0458x; 1.0458x over previous
//
#include <hip/hip_runtime.h>
#include <hip/hip_fp16.h>

#define IN_DIM 256
#define HID 128

using bf16x8 = __attribute__((ext_vector_type(8))) short;
using f32x4 = __attribute__((ext_vector_type(4))) float;

struct h8 { __half2 a, b, c, d; };  // 16B = 8 halves

__device__ __forceinline__ unsigned short f2bf(float f) {
    unsigned u = __float_as_uint(f);
    u += 0x7fffu + ((u >> 16) & 1u);  // RNE (inputs finite)
    return (unsigned short)(u >> 16);
}

// ---------- merged weight transpose+convert for the 3 live weights ----------
__device__ __forceinline__ void wt_cvt_one(const float* __restrict__ W,
                                           short* __restrict__ Wt, int idx) {
    const int kkblk = idx >> 10;
    const int n = (idx >> 3) & 127;
    const int t = idx & 7;
    const int k = (kkblk << 3) | t;
    Wt[idx] = (short)f2bf(W[(size_t)k * HID + n]);
}

__global__ __launch_bounds__(256) void wtcvt3_k(const float* __restrict__ linW0,
                                                const float* __restrict__ Ws0,
                                                const float* __restrict__ Ws5,
                                                short* __restrict__ wtl,
                                                short* __restrict__ wtc0,
                                                short* __restrict__ wtc5) {
    const int idx = blockIdx.x * blockDim.x + threadIdx.x;
    if (idx < 32768) {
        wt_cvt_one(linW0, wtl, idx);
    } else if (idx < 49152) {
        wt_cvt_one(Ws0, wtc0, idx - 32768);
    } else if (idx < 65536) {
        wt_cvt_one(Ws5, wtc5, idx - 49152);
    }
}

// ---------- single-block: wd{1,2} = Wd[l,0]@ad[l,0]; v2 = linW2@wd1; c2 = linb2·wd1 ----
__global__ __launch_bounds__(256) void wdv2_k(const float* __restrict__ Wd,
                                              const float* __restrict__ ad,
                                              const float* __restrict__ lin_W,
                                              const float* __restrict__ lin_b,
                                              float* __restrict__ wd_out,  // [2*128]
                                              float* __restrict__ v2,      // [256]
                                              float* __restrict__ c2) {
    __shared__ float wd1s[HID];
    const int t = threadIdx.x;  // 0..255
    const int l = t >> 7, j = t & 127;
    const float* w = Wd + ((size_t)(l * 5) * HID + j) * HID;
    const float* a = ad + (size_t)(l * 5) * HID;
    float s = 0.f;
    for (int k = 0; k < HID; ++k) s += w[k] * a[k];
    wd_out[t] = s;
    if (l == 0) wd1s[j] = s;
    __syncthreads();
    const float* wr = lin_W + 2 * (size_t)IN_DIM * HID + (size_t)t * HID;
    float p = 0.f;
    for (int k = 0; k < HID; ++k) p += wr[k] * wd1s[k];
    v2[t] = p;
    if (t == 0) {
        const float* br = lin_b + 2 * HID;
        float q = 0.f;
        for (int k = 0; k < HID; ++k) q += br[k] * wd1s[k];
        c2[0] = q;
    }
}

// ---------- MFMA GEMM (single weight): C[N,128] = A[N,K] @ Wt (+bias) ----------
template <int K>
__global__ __launch_bounds__(256) void gemm_mfma(const float* __restrict__ A,
                                                 const short* __restrict__ Wt,
                                                 const float* __restrict__ bias,
                                                 float* __restrict__ C, int N) {
    const int tid = threadIdx.x;
    const int w = tid >> 6;
    const int lane = tid & 63;
    const int m16 = lane & 15;
    const int kg = lane >> 4;

    const int arow = blockIdx.x * 64 + w * 16 + m16;
    const bool ok = arow < N;

    f32x4 acc[8];
#pragma unroll
    for (int j = 0; j < 8; ++j) acc[j] = (f32x4){0.f, 0.f, 0.f, 0.f};

    for (int k0 = 0; k0 < K; k0 += 32) {
        bf16x8 af = {0, 0, 0, 0, 0, 0, 0, 0};
        if (ok) {
            const float* ap = A + (size_t)arow * K + k0 + kg * 8;
            const float4 f0 = *reinterpret_cast<const float4*>(ap);
            const float4 f1 = *reinterpret_cast<const float4*>(ap + 4);
            af[0] = (short)f2bf(f0.x); af[1] = (short)f2bf(f0.y);
            af[2] = (short)f2bf(f0.z); af[3] = (short)f2bf(f0.w);
            af[4] = (short)f2bf(f1.x); af[5] = (short)f2bf(f1.y);
            af[6] = (short)f2bf(f1.z); af[7] = (short)f2bf(f1.w);
        }
        const short* bbase = Wt + (((k0 >> 3) + kg) << 10);
#pragma unroll
        for (int j = 0; j < 8; ++j) {
            const bf16x8 bf = *reinterpret_cast<const bf16x8*>(bbase + ((j * 16 + m16) << 3));
            acc[j] = __builtin_amdgcn_mfma_f32_16x16x32_bf16(af, bf, acc[j], 0, 0, 0);
        }
    }

    const int rbase = blockIdx.x * 64 + w * 16 + kg * 4;
    float bj[8];
#pragma unroll
    for (int j = 0; j < 8; ++j) bj[j] = bias ? bias[j * 16 + m16] : 0.f;
#pragma unroll
    for (int j = 0; j < 8; ++j)
#pragma unroll
        for (int r = 0; r < 4; ++r) {
            const int row = rbase + r;
            if (row < N) C[(size_t)row * HID + j * 16 + m16] = acc[j][r] + bj[j];
        }
}

// ---------- dual MFMA GEMM: hs[N][256](fp16) = A[N,128] @ {Wt0|Wt1}, fused as1/as2 ----
__global__ __launch_bounds__(256) void gemm_dual_k(const float* __restrict__ A,
                                                   const short* __restrict__ Wt0,
                                                   const short* __restrict__ Wt1,
                                                   __half* __restrict__ C,
                                                   float* __restrict__ as1,
                                                   float* __restrict__ as2,
                                                   const float* __restrict__ a1v,
                                                   const float* __restrict__ a2v, int N) {
    const int tid = threadIdx.x;
    const int w = tid >> 6;
    const int lane = tid & 63;
    const int m16 = lane & 15;
    const int kg = lane >> 4;

    const int arow = blockIdx.x * 64 + w * 16 + m16;
    const bool ok = arow < N;

    f32x4 acc[16];
#pragma unroll
    for (int j = 0; j < 16; ++j) acc[j] = (f32x4){0.f, 0.f, 0.f, 0.f};

    for (int k0 = 0; k0 < HID; k0 += 32) {
        bf16x8 af = {0, 0, 0, 0, 0, 0, 0, 0};
        if (ok) {
            const float* ap = A + (size_t)arow * HID + k0 + kg * 8;
            const float4 f0 = *reinterpret_cast<const float4*>(ap);
            const float4 f1 = *reinterpret_cast<const float4*>(ap + 4);
            af[0] = (short)f2bf(f0.x); af[1] = (short)f2bf(f0.y);
            af[2] = (short)f2bf(f0.z); af[3] = (short)f2bf(f0.w);
            af[4] = (short)f2bf(f1.x); af[5] = (short)f2bf(f1.y);
            af[6] = (short)f2bf(f1.z); af[7] = (short)f2bf(f1.w);
        }
        const int boff = ((k0 >> 3) + kg) << 10;
        const short* b0 = Wt0 + boff;
        const short* b1 = Wt1 + boff;
#pragma unroll
        for (int j = 0; j < 8; ++j) {
            const bf16x8 bf0 = *reinterpret_cast<const bf16x8*>(b0 + ((j * 16 + m16) << 3));
            acc[j] = __builtin_amdgcn_mfma_f32_16x16x32_bf16(af, bf0, acc[j], 0, 0, 0);
            const bf16x8 bf1 = *reinterpret_cast<const bf16x8*>(b1 + ((j * 16 + m16) << 3));
            acc[j + 8] = __builtin_amdgcn_mfma_f32_16x16x32_bf16(af, bf1, acc[j + 8], 0, 0, 0);
        }
    }

    const int rbase = blockIdx.x * 64 + w * 16 + kg * 4;
#pragma unroll
    for (int j = 0; j < 16; ++j)
#pragma unroll
        for (int r = 0; r < 4; ++r) {
            const int row = rbase + r;
            if (row < N) C[(size_t)row * 256 + j * 16 + m16] = __float2half(acc[j][r]);
        }

    float p1[4] = {0.f, 0.f, 0.f, 0.f};
    float p2[4] = {0.f, 0.f, 0.f, 0.f};
#pragma unroll
    for (int j = 0; j < 8; ++j) {
        const float a1 = a1v[j * 16 + m16];
        const float a2 = a2v[j * 16 + m16];
#pragma unroll
        for (int r = 0; r < 4; ++r) {
            p1[r] += acc[j][r] * a1;
            p2[r] += acc[j + 8][r] * a2;
        }
    }
#pragma unroll
    for (int off = 8; off > 0; off >>= 1)
#pragma unroll
        for (int r = 0; r < 4; ++r) {
            p1[r] += __shfl_xor(p1[r], off, 64);
            p2[r] += __shfl_xor(p2[r], off, 64);
        }
    if (m16 == 0)
#pragma unroll
        for (int r = 0; r < 4; ++r) {
            const int row = rbase + r;
            if (row < N) {
                as1[row] = p1[r];
                as2[row] = p2[r];
            }
        }
}

// ================= CSR build for the single live relation ==========
__global__ __launch_bounds__(256) void hist_k(const int* __restrict__ dst,
                                              int* __restrict__ deg, int E) {
    const int e = blockIdx.x * blockDim.x + threadIdx.x;
    if (e < E) atomicAdd(deg + dst[e], 1);
}

__global__ __launch_bounds__(256) void scan_partial_k(const int* __restrict__ deg,
                                                      int* __restrict__ partial, int total) {
    const int tid = threadIdx.x;
    const int base = blockIdx.x * 1024 + tid * 4;
    int s = 0;
#pragma unroll
    for (int i = 0; i < 4; ++i) {
        const int idx = base + i;
        if (idx < total) s += deg[idx];
    }
    __shared__ int red[4];
    int w = s;
#pragma unroll
    for (int off = 32; off > 0; off >>= 1) w += __shfl_xor(w, off, 64);
    if ((tid & 63) == 0) red[tid >> 6] = w;
    __syncthreads();
    if (tid == 0) partial[blockIdx.x] = red[0] + red[1] + red[2] + red[3];
}

__global__ __launch_bounds__(256) void scan_partials_k(int* __restrict__ partial, int nb) {
    __shared__ int sc[256];
    const int tid = threadIdx.x;
    const int v = (tid < nb) ? partial[tid] : 0;
    sc[tid] = v;
    __syncthreads();
    for (int off = 1; off < 256; off <<= 1) {
        const int u = (tid >= off) ? sc[tid - off] : 0;
        __syncthreads();
        sc[tid] += u;
        __syncthreads();
    }
    if (tid < nb) partial[tid] = sc[tid] - v;  // exclusive
}

__global__ __launch_bounds__(256) void scan_write_k(const int* __restrict__ deg,
                                                    const int* __restrict__ partial,
                                                    int* __restrict__ row_ptr,
                                                    int* __restrict__ cursor, int total,
                                                    int grand_total) {
    const int tid = threadIdx.x;
    const int base = blockIdx.x * 1024 + tid * 4;
    int v[4];
    int s = 0;
#pragma unroll
    for (int i = 0; i < 4; ++i) {
        const int idx = base + i;
        v[i] = (idx < total) ? deg[idx] : 0;
        s += v[i];
    }
    __shared__ int sc[256];
    sc[tid] = s;
    __syncthreads();
    for (int off = 1; off < 256; off <<= 1) {
        const int u = (tid >= off) ? sc[tid - off] : 0;
        __syncthreads();
        sc[tid] += u;
        __syncthreads();
    }
    int run = partial[blockIdx.x] + sc[tid] - s;
#pragma unroll
    for (int i = 0; i < 4; ++i) {
        const int idx = base + i;
        if (idx < total) {
            row_ptr[idx] = run;
            cursor[idx] = run;
            run += v[i];
        }
    }
    if (blockIdx.x == 0 && tid == 0) row_ptr[total] = grand_total;
}

__global__ __launch_bounds__(256) void scatter_k(const int* __restrict__ src,
                                                 const int* __restrict__ dst,
                                                 int* __restrict__ cursor,
                                                 int* __restrict__ col, int E) {
    const int e = blockIdx.x * blockDim.x + threadIdx.x;
    if (e >= E) return;
    const int pos = atomicAdd(cursor + dst[e], 1);
    col[pos] = src[e];
}

// ========== fully fused 2-layer GAT, 16 lanes / dst row, register-cached edges ======
__global__ __launch_bounds__(256) void gat_fused_k(
    const int* __restrict__ row_ptr, const int* __restrict__ col,
    const float* __restrict__ x_span, const float* __restrict__ v2,
    const float* __restrict__ c2, const float* __restrict__ as1,
    const float* __restrict__ as2, const __half* __restrict__ hs,
    const float* __restrict__ b1, const float* __restrict__ wd2v,
    const float* __restrict__ b2, const float* __restrict__ outW,
    const float* __restrict__ outb, float* __restrict__ out, int Ndst) {
    const int gidx = blockIdx.x * blockDim.x + threadIdx.x;
    const int row = gidx >> 4;
    const int sl = threadIdx.x & 15;
    const int grp = threadIdx.x & 48;  // group base lane within wave
    if (row >= Ndst) return;
    const int beg = row_ptr[row];
    const int end = row_ptr[row + 1];
    const int deg = end - beg;

    // ---- ad1 = x_span[row]·v2 + c2 ----
    float p = 0.f;
    const float* xr = x_span + (size_t)row * IN_DIM + sl * 16;
    const float* vr = v2 + sl * 16;
#pragma unroll
    for (int i = 0; i < 4; ++i) {
        const float4 xv = *reinterpret_cast<const float4*>(xr + i * 4);
        const float4 vv = *reinterpret_cast<const float4*>(vr + i * 4);
        p += xv.x * vv.x + xv.y * vv.y + xv.z * vv.z + xv.w * vv.w;
    }
#pragma unroll
    for (int off = 8; off > 0; off >>= 1) p += __shfl_xor(p, off, 64);
    float ad = p + c2[0];

    // ---- edge cache: lane sl owns edge beg+sl (covers deg<=16, ~99.99% of rows) ----
    const int ce = (sl < deg) ? col[beg + sl] : 0;
    const float a1c = (sl < deg) ? as1[ce] : 0.f;
    const float a2c = (sl < deg) ? as2[ce] : 0.f;
    const bool small = (deg <= 16);

#pragma unroll
    for (int layer = 0; layer < 2; ++layer) {
        const float* as_s = layer ? as2 : as1;
        const float ac = layer ? a2c : a1c;
        const int hoff = layer ? HID : 0;
        const float* bias = layer ? b2 : b1;
        const float* dvec = layer ? outW : wd2v;

        f32x4 acc0 = {0.f, 0.f, 0.f, 0.f}, acc1 = {0.f, 0.f, 0.f, 0.f};

        if (small) {
            // all-register softmax
            float t0 = ac + ad;
            t0 = t0 > 0.f ? t0 : 0.2f * t0;
            float ev = (sl < deg) ? t0 : -1e30f;
            float m = ev;
#pragma unroll
            for (int off = 8; off > 0; off >>= 1) m = fmaxf(m, __shfl_xor(m, off, 64));
            float ex = (sl < deg) ? expf(ev - m) : 0.f;
            float dsum = ex;
#pragma unroll
            for (int off = 8; off > 0; off >>= 1) dsum += __shfl_xor(dsum, off, 64);
            const float alpha = ex / (dsum + 1e-16f);

            // gather: independent 16B fp16 loads, alpha/src broadcast by shfl
            for (int i = 0; i < deg; ++i) {
                const int s = __shfl(ce, grp | i, 64);
                const float a = __shfl(alpha, grp | i, 64);
                const h8 hv = *reinterpret_cast<const h8*>(hs + (size_t)s * 256 + hoff +
                                                           sl * 8);
                const float2 f0 = __half22float2(hv.a);
                const float2 f1 = __half22float2(hv.b);
                const float2 f2 = __half22float2(hv.c);
                const float2 f3 = __half22float2(hv.d);
                acc0[0] += a * f0.x; acc0[1] += a * f0.y;
                acc0[2] += a * f1.x; acc0[3] += a * f1.y;
                acc1[0] += a * f2.x; acc1[1] += a * f2.y;
                acc1[2] += a * f3.x; acc1[3] += a * f3.y;
            }
        } else {
            // general path (deg > 16): online softmax with loads
            float m = -INFINITY, dsum = 0.f;
            for (int base = beg; base < end; base += 16) {
                const int e = base + sl;
                float ev = -INFINITY;
                if (e < end) {
                    const float t0 = as_s[col[e]] + ad;
                    ev = t0 > 0.f ? t0 : 0.2f * t0;
                }
                float gm = ev;
#pragma unroll
                for (int off = 8; off > 0; off >>= 1) gm = fmaxf(gm, __shfl_xor(gm, off, 64));
                float ex = (e < end) ? expf(ev - gm) : 0.f;
#pragma unroll
                for (int off = 8; off > 0; off >>= 1) ex += __shfl_xor(ex, off, 64);
                dsum = dsum * expf(m - gm) + ex;
                m = gm;
            }
            const float inv = 1.f / (dsum + 1e-16f);
            for (int e = beg; e < end; ++e) {
                const int s = col[e];
                float t0 = as_s[s] + ad;
                t0 = t0 > 0.f ? t0 : 0.2f * t0;
                const float a = expf(t0 - m) * inv;
                const h8 hv = *reinterpret_cast<const h8*>(hs + (size_t)s * 256 + hoff +
                                                           sl * 8);
                const float2 f0 = __half22float2(hv.a);
                const float2 f1 = __half22float2(hv.b);
                const float2 f2 = __half22float2(hv.c);
                const float2 f3 = __half22float2(hv.d);
                acc0[0] += a * f0.x; acc0[1] += a * f0.y;
                acc0[2] += a * f1.x; acc0[3] += a * f1.y;
                acc1[0] += a * f2.x; acc1[1] += a * f2.y;
                acc1[2] += a * f3.x; acc1[3] += a * f3.y;
            }
        }

        // epilogue: relu(acc+bias)·dvec, 16-lane reduce
        const f32x4 bb0 = *reinterpret_cast<const f32x4*>(bias + sl * 8);
        const f32x4 bb1 = *reinterpret_cast<const f32x4*>(bias + sl * 8 + 4);
        const f32x4 d0 = *reinterpret_cast<const f32x4*>(dvec + sl * 8);
        const f32x4 d1 = *reinterpret_cast<const f32x4*>(dvec + sl * 8 + 4);
        float q = 0.f;
#pragma unroll
        for (int i = 0; i < 4; ++i) {
            q += fmaxf(acc0[i] + bb0[i], 0.f) * d0[i];
            q += fmaxf(acc1[i] + bb1[i], 0.f) * d1[i];
        }
#pragma unroll
        for (int off = 8; off > 0; off >>= 1) q += __shfl_xor(q, off, 64);
        if (layer == 0) {
            ad = q;  // becomes ad2 for layer 2 (uniform across the 16-lane group)
        } else if (sl == 0) {
            out[row] = q + outb[0];
        }
    }
}

extern "C" void kernel_launch(void* const* d_in, const int* in_sizes, int n_in,
                              void* d_out, int out_size, void* d_ws, size_t ws_size,
                              hipStream_t stream) {
    // Live dataflow: out = relu(gat2)·outW + outb over QENT->SPAN only (see R4/R5).
    const float* x_qent = (const float*)d_in[0];
    const float* x_span = (const float*)d_in[2];
    const int* e_qs = (const int*)d_in[4];  // [2][E]
    const float* lin_W = (const float*)d_in[9];
    const float* lin_b = (const float*)d_in[10];
    const float* conv_Ws = (const float*)d_in[11];
    const float* conv_Wd = (const float*)d_in[12];
    const float* conv_as = (const float*)d_in[13];
    const float* conv_ad = (const float*)d_in[14];
    const float* conv_b = (const float*)d_in[15];
    const float* out_W = (const float*)d_in[16];
    const float* out_b = (const float*)d_in[17];

    const int NQ = in_sizes[0] / IN_DIM;
    const int NS = in_sizes[2] / IN_DIM;
    const int E = in_sizes[4] / 2;
    const int* srcp = e_qs;
    const int* dstp = e_qs + E;
    (void)n_in; (void)out_size;

    // ---- workspace carve ----
    float* ws = (float*)d_ws;
    size_t off = 0;
    auto alloc = [&](size_t n) { float* p = ws + off; off += n; return p; };
    float* xq = alloc((size_t)NQ * HID);
    __half* hs = (__half*)alloc((size_t)NQ * 128);  // fp16 [NQ][256]
    float* as1 = alloc(NQ);
    float* as2 = alloc(NQ);
    float* wd2 = alloc(2 * HID);
    float* v2 = alloc(IN_DIM);
    float* c2 = alloc(1);
    int* deg = (int*)alloc(NS);
    int* cursor = (int*)alloc(NS);
    int* row_ptr = (int*)alloc((size_t)NS + 1);
    int* partial = (int*)alloc(256);
    int* col = (int*)alloc(E);
    short* wt_lin0 = (short*)alloc(IN_DIM * HID / 2);
    short* wt_conv0 = (short*)alloc(HID * HID / 2);
    short* wt_conv5 = (short*)alloc(HID * HID / 2);
    (void)ws_size;

    // 0a. merged weight convert + merged wd/v2/c2 prep
    wtcvt3_k<<<dim3(65536 / 256), dim3(256), 0, stream>>>(
        lin_W, conv_Ws, conv_Ws + 5 * (size_t)HID * HID, wt_lin0, wt_conv0, wt_conv5);
    wdv2_k<<<dim3(1), dim3(256), 0, stream>>>(conv_Wd, conv_ad, lin_W, lin_b, wd2, v2, c2);

    // 0b. dst-CSR for r0
    const int nb = (NS + 1023) / 1024;
    hipMemsetAsync(deg, 0, (size_t)NS * 4, stream);
    hist_k<<<dim3((E + 255) / 256), dim3(256), 0, stream>>>(dstp, deg, E);
    scan_partial_k<<<dim3(nb), dim3(256), 0, stream>>>(deg, partial, NS);
    scan_partials_k<<<dim3(1), dim3(256), 0, stream>>>(partial, nb);
    scan_write_k<<<dim3(nb), dim3(256), 0, stream>>>(deg, partial, row_ptr, cursor, NS, E);
    scatter_k<<<dim3((E + 255) / 256), dim3(256), 0, stream>>>(srcp, dstp, cursor, col, E);

    // 1. QENT projection, then both layers' hs (fp16) + fused as1/as2
    gemm_mfma<IN_DIM><<<dim3((NQ + 63) / 64), dim3(256), 0, stream>>>(
        x_qent, wt_lin0, lin_b, xq, NQ);
    gemm_dual_k<<<dim3((NQ + 63) / 64), dim3(256), 0, stream>>>(
        xq, wt_conv0, wt_conv5, hs, as1, as2, conv_as, conv_as + 5 * (size_t)HID, NQ);

    // 2. one fused kernel: ad1 matvec + both GAT layers + final projection
    gat_fused_k<<<dim3(((size_t)NS * 16 + 255) / 256), dim3(256), 0, stream>>>(
        row_ptr, col, x_span, v2, c2, as1, as2, hs, conv_b, wd2 + HID,
        conv_b + 5 * (size_t)HID, out_W, out_b, (float*)d_out, NS);
}